// Round 4
// baseline (59.863 us; speedup 1.0000x reference)
//
#include <hip/hip_runtime.h>

// Fused: reshape -> 1x1 mix (w1) -> double-unfold conv (w0) -> reshape -> roll(+1, H)
//
// Math per output (c = 4l + p, h, n), with o = (h-1) mod 56:
//   t4[p,j,n]  = sum_q x[2q+j, o, n] * w1[p,q]            (q in [0,64))
//   out[c,h,n] = sum_{j,k,i} w0[l,j,i,k] * t4[p,j, n+k+i-2]
//                gated on (0 <= n+k-1 < 56) AND (0 <= n+k+i-2 < 56)
// i-gate: zero pad of 2 on each side of the t4 row. k-gate: branchless select
// of the per-k partial sum (two-stage-unfold semantics).
//
// Round 4: 512-thread block. t4 split 2-way over q (32 loads/thread, shfl_xor
// combine). Conv: thread=(l, g=float4 group), 8-float t4 window -> registers
// (2x ds_read_b128 per j), 4 outputs, one float4 store.

__global__ __launch_bounds__(512) void fused_shift_unfold_kernel(
    const float* __restrict__ x,    // [128,56,56]
    const float* __restrict__ w0,   // [32,2,3,3]
    const float* __restrict__ w1,   // [4,64]
    float* __restrict__ out)        // [128,56,56]
{
    __shared__ float s_t4[2][60];    // s_t4[j][n+2] = t4[p,j,n]; pad 2 each side
    __shared__ float s_w0[576];      // [l][j][i][k]

    const int tid = threadIdx.x;
    const int h   = blockIdx.x;           // output H row
    const int p   = blockIdx.y;           // p = c & 3
    const int o   = h ? h - 1 : 55;       // source H row (roll by +1)

    if (tid < 224) {
        // ---- t4: 2 threads per value, 32 strided L2 loads each ----
        const int v    = tid >> 1;        // [0,112)
        const int half = tid & 1;
        const int j    = (v >= 56);
        const int n    = v - j * 56;
        const float* xp = x + j * 3136 + o * 56 + n + half * 32 * 6272;
        const float* wp = w1 + p * 64 + half * 32;     // wave-uniform -> s_load
        float a0 = 0.f, a1 = 0.f, a2 = 0.f, a3 = 0.f;
        #pragma unroll
        for (int q = 0; q < 32; q += 4) {
            a0 += wp[q + 0] * xp[(q + 0) * 6272];
            a1 += wp[q + 1] * xp[(q + 1) * 6272];
            a2 += wp[q + 2] * xp[(q + 2) * 6272];
            a3 += wp[q + 3] * xp[(q + 3) * 6272];
        }
        float a = (a0 + a1) + (a2 + a3);
        float b = __shfl_xor(a, 1);       // partner lanes 2v / 2v+1, same wave
        if (half == 0) s_t4[j][n + 2] = a + b;
    } else if (tid < 368) {
        // ---- stage w0 (144 threads x float4) + zero pads ----
        const int t = tid - 224;          // [0,144)
        ((float4*)s_w0)[t] = ((const float4*)w0)[t];
        if (t < 8) {                      // pads: [j][0,1,58,59]
            const int j  = t & 1;
            const int q2 = t >> 1;        // 0..3
            s_t4[j][q2 < 2 ? q2 : q2 + 56] = 0.f;
        }
    }
    __syncthreads();

    // ---- conv + store: thread = (l, g); 4 outputs n = g*4+u, float4 store ----
    const int g = tid & 15;               // float4 group; valid if g < 14
    const int l = tid >> 4;               // [0,32)
    if (g < 14) {
        float wreg[2][9];                 // wreg[j][i*3+k]
        #pragma unroll
        for (int j = 0; j < 2; ++j)
            #pragma unroll
            for (int t = 0; t < 9; ++t)
                wreg[j][t] = s_w0[l * 18 + j * 9 + t];

        // 8-float t4 window -> registers (contiguous, 16B-aligned: 2x b128/j)
        float r[2][8];                    // r[j][d] = t4[p,j, g*4 + d - 2]
        #pragma unroll
        for (int j = 0; j < 2; ++j)
            #pragma unroll
            for (int d = 0; d < 8; ++d)
                r[j][d] = s_t4[j][g * 4 + d];

        float4 res;
        float* rf = (float*)&res;
        #pragma unroll
        for (int u = 0; u < 4; ++u) {
            const int n = g * 4 + u;
            float acc = 0.f;
            #pragma unroll
            for (int k = 0; k < 3; ++k) {
                float s = 0.f;
                #pragma unroll
                for (int j = 0; j < 2; ++j) {
                    s += wreg[j][0 + k] * r[j][u + k + 0];  // i=0
                    s += wreg[j][3 + k] * r[j][u + k + 1];  // i=1
                    s += wreg[j][6 + k] * r[j][u + k + 2];  // i=2
                }
                const int m = n + k - 1;                    // first-unfold pos
                acc += ((unsigned)m < 56u) ? s : 0.f;
            }
            rf[u] = acc;
        }
        float* obase = out + (l * 4 + p) * 3136 + h * 56 + g * 4;
        *(float4*)obase = res;
    }
}

extern "C" void kernel_launch(void* const* d_in, const int* in_sizes, int n_in,
                              void* d_out, int out_size, void* d_ws, size_t ws_size,
                              hipStream_t stream) {
    (void)in_sizes; (void)n_in; (void)out_size; (void)d_ws; (void)ws_size;
    const float* x  = (const float*)d_in[0];   // [1,128,56,56]
    const float* w0 = (const float*)d_in[1];   // [32,2,3,3]
    const float* w1 = (const float*)d_in[2];   // [4,64]
    float* out = (float*)d_out;                // [1,128,56,56]

    dim3 grid(56, 4);
    fused_shift_unfold_kernel<<<grid, 512, 0, stream>>>(x, w0, w1, out);
}